// Round 4
// baseline (1286.551 us; speedup 1.0000x reference)
//
#include <hip/hip_runtime.h>
#include <hip/hip_bf16.h>
#include <stdint.h>

#define IGNORE_INDEX (-100)

constexpr int M_ = 8192;    // B*S tokens
constexpr int K_ = 2048;    // D
constexpr int N_ = 32000;   // V

typedef __attribute__((ext_vector_type(4)))  float f32x4;
typedef __attribute__((ext_vector_type(16))) float f32x16;
typedef __attribute__((ext_vector_type(4)))  int   i32x4;
typedef __attribute__((ext_vector_type(8)))  int   i32x8;
typedef __attribute__((ext_vector_type(4)))  unsigned int u32x4;
typedef __attribute__((ext_vector_type(8)))  __bf16 bf16x8;

// quantization scales (powers of 2, exactly undone in fp32 epilogue)
#define SCALE_A 8.0f
#define SCALE_W 1024.0f
#define INV_S   (1.0f / (8.0f * 1024.0f))

// ---------- fp32 -> bf16 packing (fallback path) ----------
__device__ __forceinline__ unsigned pack_bf16(float f0, float f1) {
    unsigned u0 = __builtin_bit_cast(unsigned, f0) + 0x8000u;
    unsigned u1 = __builtin_bit_cast(unsigned, f1) + 0x8000u;
    return __builtin_amdgcn_perm(u1, u0, 0x07060302u);
}
__device__ __forceinline__ u32x4 pack8(f32x4 lo, f32x4 hi) {
    u32x4 r;
    r[0] = pack_bf16(lo[0], lo[1]);
    r[1] = pack_bf16(lo[2], lo[3]);
    r[2] = pack_bf16(hi[0], hi[1]);
    r[3] = pack_bf16(hi[2], hi[3]);
    return r;
}

// ---------- async global->LDS, 16B per lane ----------
__device__ __forceinline__ void gll16(const void* g, void* l) {
    __builtin_amdgcn_global_load_lds(
        (const __attribute__((address_space(1))) unsigned int*)g,
        (__attribute__((address_space(3))) unsigned int*)l, 16, 0, 0);
}

__global__ void init_acc(float* p, int n) {
    int i = blockIdx.x * 256 + threadIdx.x;
    if (i < n) p[i] = 0.0f;
}

// n8 groups of 8 fp32 -> 8 fp8 e4m3 (scaled)
__global__ __launch_bounds__(256) void convert_fp8(
    const float* __restrict__ in, unsigned int* __restrict__ out,
    float scale, int n8)
{
    int i = blockIdx.x * 256 + threadIdx.x;
    if (i < n8) {
        f32x4 lo = ((const f32x4*)in)[2 * i];
        f32x4 hi = ((const f32x4*)in)[2 * i + 1];
        int w0 = 0, w1 = 0;
        w0 = __builtin_amdgcn_cvt_pk_fp8_f32(lo[0] * scale, lo[1] * scale, w0, false);
        w0 = __builtin_amdgcn_cvt_pk_fp8_f32(lo[2] * scale, lo[3] * scale, w0, true);
        w1 = __builtin_amdgcn_cvt_pk_fp8_f32(hi[0] * scale, hi[1] * scale, w1, false);
        w1 = __builtin_amdgcn_cvt_pk_fp8_f32(hi[2] * scale, hi[3] * scale, w1, true);
        out[2 * i]     = (unsigned int)w0;
        out[2 * i + 1] = (unsigned int)w1;
    }
}

// ======== MX-fp8 GEMM: 256x256 tile, BK=128, 4-phase counted-vmcnt ==========
// Round-8: faithful port of the verified 8-phase 256-sq bf16 template at
// MATCHING byte geometry (fp8 BK=128 B == bf16 BK=64 rows of 128 B).
// 512 thr / 8 waves (2M x 4N), wave tile 128x64, 32x32x64 MFMA.
// Per K-tile: 4 phases x {ds_reads || 2 gll16 -> bar -> lgkm0 -> 4 MFMA ->
// bar}; ONE boundary s_waitcnt vmcnt(6) per K-tile (never 0 in main loop).
// Mechanism: s_barrier waits on wave ARRIVAL, not MFMA completion -> phase
// p's reads/stages issue under phase p-1's draining MFMAs; 1100 cyc of
// MFMA per K-tile per SIMD vs ~1500 cyc LDS traffic per CU (68%) -> MFMA
// pipe stays fed. LDS 128 KB (dynamic) -> 1 block/CU, 8 waves (HK config).
// Chunks: A/B tile = 4 chunks x 64 rows x 128 B (8 KB = 512 thr x 16 B).
// Reads: A chunks {0,2}@p0, {1,3}@p2 (per-wm); B chunk wn @p0,p1.
// Stage stream during tile t (FIFO, per-wave 8/tile):
//   p0: (t+1,A1),(t+1,A3) -> buf[t+1]   (other buffer, always safe)
//   p1: (t+2,A0),(t+2,A2) -> buf[t]     (A0/A2 last read @p0, bar between)
//   p2: (t+2,B0),(t+2,B1) -> buf[t]     (B last read @p1)
//   p3: (t+2,B2),(t+2,B3) -> buf[t]
// Boundary vmcnt(6): newest 6 = t+2's chunks; everything tile t+1 reads is
// retired (its A1,A3 = this tile's p0 = position -8..-7).
// Swizzle (bank-conflict fix for 128-B rows, 16-way otherwise): 16B-unit
// off16 ^= (row>>2)&7, applied to pre-swizzled GLOBAL source on stage and
// to the frag-read address (involution). gll16 dest stays linear (m104).
// Frag layouts (numerics-verified r3-r7): A/B lane l -> row l&31, K-bytes
// ks*64 + (l>>5)*32 (+16 part); C/D col=lane&31, row=(reg&3)+8(reg>>2)+4h.

#define MFMA_SC(a, b, c) \
    __builtin_amdgcn_mfma_scale_f32_32x32x64_f8f6f4( \
        (a), (b), (c), 0, 0, 0, 0x7F7F7F7F, 0, 0x7F7F7F7F)

#define CAT8(lo, hi) (i32x8){(lo)[0], (lo)[1], (lo)[2], (lo)[3], \
                             (hi)[0], (hi)[1], (hi)[2], (hi)[3]}

#define LGKM0() do { \
    asm volatile("s_waitcnt lgkmcnt(0)" ::: "memory"); \
    __builtin_amdgcn_sched_barrier(0); \
} while (0)

#define PREBAR() do { \
    __builtin_amdgcn_sched_barrier(0); \
    __builtin_amdgcn_s_barrier(); \
} while (0)

constexpr size_t CA = (size_t)64 * K_;   // chunk stride in global (64 rows)

template <bool S0, bool S1, int BVM>
__device__ __forceinline__ void ktile(
    const unsigned char* cA, const unsigned char* cB,   // compute buffers
    unsigned char* nA,                                  // buf[t+1] A (p0 stage)
    unsigned char* wA, unsigned char* wB,               // buf[t+2] = buf[t]
    const unsigned char* gA, const unsigned char* gB, int kt, int t16,
    const int (&bA)[4][2], const int (&bB)[2][2],
    f32x16 (&acc)[4][2])
{
    // ---- P0: read A m0,m1 (both ks) + B n0; stage (t+1) A1,A3 ----
    i32x4 r0 = *(const i32x4*)(cA + bA[0][0]);
    i32x4 r1 = *(const i32x4*)(cA + (bA[0][0] ^ 16));
    i32x4 r2 = *(const i32x4*)(cA + bA[0][1]);
    i32x4 r3 = *(const i32x4*)(cA + (bA[0][1] ^ 16));
    i32x4 r4 = *(const i32x4*)(cA + bA[1][0]);
    i32x4 r5 = *(const i32x4*)(cA + (bA[1][0] ^ 16));
    i32x4 r6 = *(const i32x4*)(cA + bA[1][1]);
    i32x4 r7 = *(const i32x4*)(cA + (bA[1][1] ^ 16));
    i32x4 s0 = *(const i32x4*)(cB + bB[0][0]);
    i32x4 s1 = *(const i32x4*)(cB + (bB[0][0] ^ 16));
    i32x4 s2 = *(const i32x4*)(cB + bB[0][1]);
    i32x4 s3 = *(const i32x4*)(cB + (bB[0][1] ^ 16));
    if (S0) {
        gll16(gA + 1 * CA + kt + 128, nA + 1 * 8192 + t16);
        gll16(gA + 3 * CA + kt + 128, nA + 3 * 8192 + t16);
    }
    PREBAR();
    LGKM0();
    i32x8 a00 = CAT8(r0, r1), a01 = CAT8(r2, r3);
    i32x8 a10 = CAT8(r4, r5), a11 = CAT8(r6, r7);
    i32x8 b00 = CAT8(s0, s1), b01 = CAT8(s2, s3);
    __builtin_amdgcn_s_setprio(1);
    acc[0][0] = MFMA_SC(a00, b00, acc[0][0]);
    acc[0][0] = MFMA_SC(a01, b01, acc[0][0]);
    acc[1][0] = MFMA_SC(a10, b00, acc[1][0]);
    acc[1][0] = MFMA_SC(a11, b01, acc[1][0]);
    __builtin_amdgcn_s_setprio(0);
    __builtin_amdgcn_s_barrier();

    // ---- P1: read B n1; stage (t+2) A0,A2 ----
    i32x4 u0 = *(const i32x4*)(cB + bB[1][0]);
    i32x4 u1 = *(const i32x4*)(cB + (bB[1][0] ^ 16));
    i32x4 u2 = *(const i32x4*)(cB + bB[1][1]);
    i32x4 u3 = *(const i32x4*)(cB + (bB[1][1] ^ 16));
    if (S1) {
        gll16(gA + 0 * CA + kt + 256, wA + 0 * 8192 + t16);
        gll16(gA + 2 * CA + kt + 256, wA + 2 * 8192 + t16);
    }
    PREBAR();
    LGKM0();
    i32x8 b10 = CAT8(u0, u1), b11 = CAT8(u2, u3);
    __builtin_amdgcn_s_setprio(1);
    acc[0][1] = MFMA_SC(a00, b10, acc[0][1]);
    acc[0][1] = MFMA_SC(a01, b11, acc[0][1]);
    acc[1][1] = MFMA_SC(a10, b10, acc[1][1]);
    acc[1][1] = MFMA_SC(a11, b11, acc[1][1]);
    __builtin_amdgcn_s_setprio(0);
    __builtin_amdgcn_s_barrier();

    // ---- P2: read A m2,m3 (overwrite a regs); stage (t+2) B0,B1 ----
    i32x4 v0 = *(const i32x4*)(cA + bA[2][0]);
    i32x4 v1 = *(const i32x4*)(cA + (bA[2][0] ^ 16));
    i32x4 v2 = *(const i32x4*)(cA + bA[2][1]);
    i32x4 v3 = *(const i32x4*)(cA + (bA[2][1] ^ 16));
    i32x4 v4 = *(const i32x4*)(cA + bA[3][0]);
    i32x4 v5 = *(const i32x4*)(cA + (bA[3][0] ^ 16));
    i32x4 v6 = *(const i32x4*)(cA + bA[3][1]);
    i32x4 v7 = *(const i32x4*)(cA + (bA[3][1] ^ 16));
    if (S1) {
        gll16(gB + 0 * CA + kt + 256, wB + 0 * 8192 + t16);
        gll16(gB + 1 * CA + kt + 256, wB + 1 * 8192 + t16);
    }
    PREBAR();
    LGKM0();
    i32x8 a20 = CAT8(v0, v1), a21 = CAT8(v2, v3);
    i32x8 a30 = CAT8(v4, v5), a31 = CAT8(v6, v7);
    __builtin_amdgcn_s_setprio(1);
    acc[2][1] = MFMA_SC(a20, b10, acc[2][1]);
    acc[2][1] = MFMA_SC(a21, b11, acc[2][1]);
    acc[3][1] = MFMA_SC(a30, b10, acc[3][1]);
    acc[3][1] = MFMA_SC(a31, b11, acc[3][1]);
    __builtin_amdgcn_s_setprio(0);
    __builtin_amdgcn_s_barrier();

    // ---- P3: no reads; stage (t+2) B2,B3; boundary vmcnt ----
    if (S1) {
        gll16(gB + 2 * CA + kt + 256, wB + 2 * 8192 + t16);
        gll16(gB + 3 * CA + kt + 256, wB + 3 * 8192 + t16);
    }
    PREBAR();
    __builtin_amdgcn_s_setprio(1);
    acc[2][0] = MFMA_SC(a20, b00, acc[2][0]);
    acc[2][0] = MFMA_SC(a21, b01, acc[2][0]);
    acc[3][0] = MFMA_SC(a30, b00, acc[3][0]);
    acc[3][0] = MFMA_SC(a31, b01, acc[3][0]);
    __builtin_amdgcn_s_setprio(0);
    if constexpr (BVM == 6) {
        asm volatile("s_waitcnt vmcnt(6)" ::: "memory");
        __builtin_amdgcn_s_barrier();
    } else if constexpr (BVM == 0) {
        asm volatile("s_waitcnt vmcnt(0)" ::: "memory");
        __builtin_amdgcn_s_barrier();
    }
}

__global__ __launch_bounds__(512, 2) void gemm_fp8(
    const unsigned char* __restrict__ A,
    const unsigned char* __restrict__ Wq,
    const int*   __restrict__ tgt,
    float* __restrict__ sumexp,
    float* __restrict__ tgtlogit)
{
    extern __shared__ unsigned char smem[];
    unsigned char* As0 = smem;                 // 32 KB
    unsigned char* As1 = smem + 32768;
    unsigned char* Bs0 = smem + 65536;
    unsigned char* Bs1 = smem + 98304;
    int* tg = (int*)(smem + 131072);           // 1 KB

    const int tid = threadIdx.x;   // 0..511
    const int bid = blockIdx.x;    // 0..3999
    const int mt  = bid & 31;      // mt fastest: 32 consecutive share W tile
    const int nt  = bid >> 5;      // 0..124

    if (tid < 256) tg[tid] = tgt[mt * 256 + tid];

    const int wave = tid >> 6;     // 0..7
    const int lane = tid & 63;
    const int wm   = wave >> 2;    // rows wm*128..+127
    const int wn   = wave & 3;     // cols wn*64..+63

    // --- staging: thread -> (row tid>>3 of chunk, 16B-unit tid&7) ---
    // global source pre-swizzled: off16 ^ ((row_in_chunk>>2)&7)
    const int sw16 = ((tid & 7) ^ ((tid >> 5) & 7)) << 4;
    const unsigned char* gA = A  + (size_t)(mt * 256 + (tid >> 3)) * K_ + sw16;
    const unsigned char* gB = Wq + (size_t)(nt * 256 + (tid >> 3)) * K_ + sw16;
    const int t16 = tid << 4;      // linear LDS dest within chunk

    // --- frag read bases: LDS byte = row*128 + ((ks*64+h*32+part*16)^xa) ---
    const int l31 = lane & 31;
    const int h   = lane >> 5;
    int bA[4][2], bB[2][2];
#pragma unroll
    for (int m = 0; m < 4; ++m) {
        const int row = wm * 128 + m * 32 + l31;
        const int xa  = ((row >> 2) & 7) << 4;
#pragma unroll
        for (int ks = 0; ks < 2; ++ks)
            bA[m][ks] = row * 128 + (((ks << 6) | (h << 5)) ^ xa);
    }
#pragma unroll
    for (int n = 0; n < 2; ++n) {
        const int row = wn * 64 + n * 32 + l31;
        const int xb  = ((row >> 2) & 7) << 4;
#pragma unroll
        for (int ks = 0; ks < 2; ++ks)
            bB[n][ks] = row * 128 + (((ks << 6) | (h << 5)) ^ xb);
    }

    f32x16 acc[4][2];
#pragma unroll
    for (int m = 0; m < 4; ++m)
#pragma unroll
        for (int n = 0; n < 2; ++n)
#pragma unroll
            for (int r = 0; r < 16; ++r) acc[m][n][r] = 0.f;

    // --- prologue: tile0 all 8 chunks; tile1 A0,A2,B0..B3 (FIFO order!) ---
#pragma unroll
    for (int c = 0; c < 4; ++c) gll16(gA + c * CA, As0 + c * 8192 + t16);
#pragma unroll
    for (int c = 0; c < 4; ++c) gll16(gB + c * CA, Bs0 + c * 8192 + t16);
    gll16(gA + 0 * CA + 128, As1 + 0 * 8192 + t16);
    gll16(gA + 2 * CA + 128, As1 + 2 * 8192 + t16);
    gll16(gB + 0 * CA + 128, Bs1 + 0 * 8192 + t16);
    gll16(gB + 1 * CA + 128, Bs1 + 1 * 8192 + t16);
    gll16(gB + 2 * CA + 128, Bs1 + 2 * 8192 + t16);
    gll16(gB + 3 * CA + 128, Bs1 + 3 * 8192 + t16);
    asm volatile("s_waitcnt vmcnt(6) lgkmcnt(0)" ::: "memory");
    __builtin_amdgcn_s_barrier();

    // --- main loop: 16 K-tiles of 128 B; tiles 0..13 full pipeline ---
    int kt = 0;
#pragma unroll 1
    for (int it = 0; it < 7; ++it) {
        ktile<true, true, 6>(As0, Bs0, As1, As0, Bs0,
                             gA, gB, kt,       t16, bA, bB, acc);
        ktile<true, true, 6>(As1, Bs1, As0, As1, Bs1,
                             gA, gB, kt + 128, t16, bA, bB, acc);
        kt += 256;
    }
    // tile 14 (kt=1792): stage only (t15,A1,A3); drain boundary
    ktile<true, false, 0>(As0, Bs0, As1, As0, Bs0,
                          gA, gB, 1792, t16, bA, bB, acc);
    // tile 15 (kt=1920): pure compute, no boundary
    ktile<false, false, -1>(As1, Bs1, As0, As1, Bs1,
                            gA, gB, 1920, t16, bA, bB, acc);

    // --- epilogue: C/D col=lane&31, row=(reg&3)+8*(reg>>2)+4h ---
    const int c0 = nt * 256 + wn * 64 + l31;
#pragma unroll
    for (int m = 0; m < 4; ++m) {
#pragma unroll
        for (int reg = 0; reg < 16; ++reg) {
            const int rbase = (reg & 3) + 8 * (reg >> 2) + 4 * h;
            const int lrow  = wm * 128 + m * 32 + rbase;
            const int grow  = mt * 256 + lrow;
            const int t     = tg[lrow];
            float v0 = acc[m][0][reg] * INV_S;
            float v1 = acc[m][1][reg] * INV_S;
            if (t == c0)      tgtlogit[grow] = v0;   // cols wn*64 + 0..31
            if (t == c0 + 32) tgtlogit[grow] = v1;   // cols wn*64 + 32..63
            float rs = __expf(v0) + __expf(v1);
            rs += __shfl_xor(rs, 1);
            rs += __shfl_xor(rs, 2);
            rs += __shfl_xor(rs, 4);
            rs += __shfl_xor(rs, 8);
            rs += __shfl_xor(rs, 16);
            if (l31 == 0) atomicAdd(&sumexp[grow], rs);
        }
    }
}

// ------------- fallback (round-1 kernel) if ws_size too small ----------------
constexpr int BMf = 128, BNf = 128;
constexpr int BKf = 32;
constexpr int LDA = BKf + 8;
__global__ __launch_bounds__(256) void gemm_fused_f32(
    const float* __restrict__ A,
    const float* __restrict__ W,
    const int*   __restrict__ tgt,
    float* __restrict__ sumexp,
    float* __restrict__ tgtlogit)
{
    __shared__ __bf16 As[BMf * LDA];
    __shared__ __bf16 Bs[BNf * LDA];
    __shared__ int    tg[BMf];

    const int tid = threadIdx.x;
    const int mt  = blockIdx.x;
    const int nt  = blockIdx.y;
    if (tid < BMf) tg[tid] = tgt[mt * BMf + tid];

    const int wave = tid >> 6, lane = tid & 63;
    const int wm = wave >> 1, wn = wave & 1;
    const int lquad = lane >> 4, lcol = lane & 15;
    const int srow = tid >> 2, scol = (tid & 3) * 8;

    const float* gA = A + (size_t)(mt * BMf + srow) * K_ + scol;
    const float* gB = W + (size_t)(nt * BNf + srow) * K_ + scol;
    const size_t rowstep = (size_t)64 * K_;

    f32x4 acc[4][4];
#pragma unroll
    for (int i = 0; i < 4; i++)
#pragma unroll
        for (int j = 0; j < 4; j++) acc[i][j] = (f32x4){0.f, 0.f, 0.f, 0.f};

    for (int kt = 0; kt < K_; kt += BKf) {
        f32x4 a0 = *(const f32x4*)(gA + kt);
        f32x4 a1 = *(const f32x4*)(gA + kt + 4);
        f32x4 a2 = *(const f32x4*)(gA + kt + rowstep);
        f32x4 a3 = *(const f32x4*)(gA + kt + rowstep + 4);
        f32x4 b0 = *(const f32x4*)(gB + kt);
        f32x4 b1 = *(const f32x4*)(gB + kt + 4);
        f32x4 b2 = *(const f32x4*)(gB + kt + rowstep);
        f32x4 b3 = *(const f32x4*)(gB + kt + rowstep + 4);
        __syncthreads();
        *(u32x4*)&As[srow * LDA + scol]        = pack8(a0, a1);
        *(u32x4*)&As[(srow + 64) * LDA + scol] = pack8(a2, a3);
        *(u32x4*)&Bs[srow * LDA + scol]        = pack8(b0, b1);
        *(u32x4*)&Bs[(srow + 64) * LDA + scol] = pack8(b2, b3);
        __syncthreads();
        bf16x8 af[4], bf[4];
#pragma unroll
        for (int f = 0; f < 4; f++) {
            af[f] = *(const bf16x8*)&As[(wm * 64 + f * 16 + lcol) * LDA + lquad * 8];
            bf[f] = *(const bf16x8*)&Bs[(wn * 64 + f * 16 + lcol) * LDA + lquad * 8];
        }
#pragma unroll
        for (int mf = 0; mf < 4; mf++)
#pragma unroll
            for (int nf = 0; nf < 4; nf++)
                acc[mf][nf] = __builtin_amdgcn_mfma_f32_16x16x32_bf16(af[mf], bf[nf], acc[mf][nf], 0, 0, 0);
    }
    const int colbase = nt * BNf + wn * 64;
#pragma unroll
    for (int mf = 0; mf < 4; mf++) {
#pragma unroll
        for (int r = 0; r < 4; r++) {
            const int lrow = wm * 64 + mf * 16 + lquad * 4 + r;
            const int grow = mt * BMf + lrow;
            const int t    = tg[lrow];
            float rs = 0.f;
#pragma unroll
            for (int nf = 0; nf < 4; nf++) {
                float v = acc[mf][nf][r];
                rs += __expf(v);
                if (t == colbase + nf * 16 + lcol) tgtlogit[grow] = v;
            }
            rs += __shfl_xor(rs, 1);
            rs += __shfl_xor(rs, 2);
            rs += __shfl_xor(rs, 4);
            rs += __shfl_xor(rs, 8);
            if (lcol == 0) atomicAdd(&sumexp[grow], rs);
        }
    }
}

__global__ __launch_bounds__(256) void finalize(
    const float* __restrict__ sumexp,
    const float* __restrict__ tgtlogit,
    const int*   __restrict__ tgt,
    float* __restrict__ out)
{
    float s = 0.f;
    int   c = 0;
    for (int i = threadIdx.x; i < M_; i += 256) {
        int t = tgt[i];
        if (t != IGNORE_INDEX) {
            s += __logf(sumexp[i]) - tgtlogit[i];
            c++;
        }
    }
#pragma unroll
    for (int o = 32; o; o >>= 1) {
        s += __shfl_down(s, o);
        c += __shfl_down(c, o);
    }
    __shared__ float ss[4];
    __shared__ int   cc[4];
    int w = threadIdx.x >> 6;
    if ((threadIdx.x & 63) == 0) { ss[w] = s; cc[w] = c; }
    __syncthreads();
    if (threadIdx.x == 0) {
        float st = ss[0] + ss[1] + ss[2] + ss[3];
        int   ct = cc[0] + cc[1] + cc[2] + cc[3];
        out[0] = st / (float)ct;
    }
}

extern "C" void kernel_launch(void* const* d_in, const int* in_sizes, int n_in,
                              void* d_out, int out_size, void* d_ws, size_t ws_size,
                              hipStream_t stream) {
    const float* hidden  = (const float*)d_in[0];
    const int*   targets = (const int*)d_in[1];
    const float* W       = (const float*)d_in[2];

    float* sumexp   = (float*)d_ws;          // [M_] f32
    float* tgtlogit = sumexp + M_;           // [M_] f32
    float* out      = (float*)d_out;

    unsigned char* Aq = (unsigned char*)d_ws + 2 * M_ * sizeof(float);
    unsigned char* Wq = Aq + (size_t)M_ * K_;
    const size_t need = 2 * M_ * sizeof(float) + (size_t)M_ * K_ + (size_t)N_ * K_;

    init_acc<<<(2 * M_ + 255) / 256, 256, 0, stream>>>(sumexp, 2 * M_);

    if (ws_size >= need) {
        static bool attr_set = false;
        if (!attr_set) {
            hipFuncSetAttribute(reinterpret_cast<const void*>(gemm_fp8),
                                hipFuncAttributeMaxDynamicSharedMemorySize,
                                132096);
            attr_set = true;
        }
        const int a8 = M_ * K_ / 8;          // 2,097,152
        const int w8 = N_ * K_ / 8;          // 8,192,000
        convert_fp8<<<(a8 + 255) / 256, 256, 0, stream>>>(hidden, (unsigned int*)Aq, SCALE_A, a8);
        convert_fp8<<<(w8 + 255) / 256, 256, 0, stream>>>(W, (unsigned int*)Wq, SCALE_W, w8);
        gemm_fp8<<<(M_ / 256) * (N_ / 256), 512, 132096, stream>>>(Aq, Wq, targets, sumexp, tgtlogit);
    } else {
        gemm_fused_f32<<<dim3(M_ / BMf, N_ / BNf), 256, 0, stream>>>(hidden, W, targets, sumexp, tgtlogit);
    }

    finalize<<<1, 256, 0, stream>>>(sumexp, tgtlogit, targets, out);
}